// Round 14
// baseline (3052.740 us; speedup 1.0000x reference)
//
#include <hip/hip_runtime.h>
#include <stdint.h>

// ====== TrajectoryLSTM r14 — single persistent kernel, block-local everything ======
#define Bsz   16384
#define Tseq  8
#define NPRED 12
#define RPB   64            // rows per block; grid = 256 = #CUs

typedef __attribute__((ext_vector_type(4))) float    f32x4;
typedef _Float16 h16;
typedef __attribute__((ext_vector_type(8))) _Float16 h16x8;

__device__ __forceinline__ float sigf(float x)   { return 1.f / (1.f + __expf(-x)); }
__device__ __forceinline__ float tanh_f(float x) { return 1.f - 2.f / (__expf(2.f * x) + 1.f); }

__device__ __forceinline__ void gload_lds16(const void* g, void* l) {
  __builtin_amdgcn_global_load_lds(
      (const __attribute__((address_space(1))) void*)g,
      (__attribute__((address_space(3))) void*)l, 16, 0, 0);
}

__global__ void mark_r14(float* __restrict__ out) {
  if (blockIdx.x == 0 && threadIdx.x < 64) out[threadIdx.x] = 1000.0f;
}

// ---- weight packing (r13 layout): slab-major [nb*KBpack+kb] blocks of [256 r][64 k]
// (32KB each), XOR-preswizzled rows; gatePack: r -> n = gi*256 + nb*64 + wc*16 + jr.
__global__ void pack_w(h16* __restrict__ dst, const float* __restrict__ W0,
                       const float* __restrict__ W1, int ksplit, int Kw, int Np,
                       int gatePack) {
  int idx = blockIdx.x * 256 + threadIdx.x;
  if (idx >= Np * Kw) return;
  int np = idx / Kw, k = idx - np * Kw;
  int nb = np >> 8, r = np & 255;
  int n = np;
  if (gatePack) {
    int wcq = r >> 6, gi = (r >> 4) & 3, jr = r & 15;
    n = gi * 256 + nb * 64 + wcq * 16 + jr;
  }
  float w = (k < ksplit) ? W0[(size_t)n * ksplit + k]
                         : W1[(size_t)n * (Kw - ksplit) + (k - ksplit)];
  int KB = Kw >> 6, kb = k >> 6;
  uint32_t byte = (uint32_t)(nb * KB + kb) * 32768u + (uint32_t)r * 128u
                + ((2u * (uint32_t)(k & 63)) ^ (uint32_t)((r & 7) << 4));
  *(h16*)((char*)dst + byte) = (h16)w;
}

__global__ void add_bias(float* __restrict__ dst, const float* __restrict__ a,
                         const float* __restrict__ b) {
  int i = blockIdx.x * 256 + threadIdx.x;
  if (i < 1024) dst[i] = a[i] + b[i];
}

// ---- one 64x256 output tile, K = KBiter*64, double-buffered staging ----
// LDS buffers: buf b at lds + b*41216: A slab 8KB, W slab 32KB.
__device__ __forceinline__ void gemm_tile(
    const char* A0, const char* A1, const char* wTile, int KBiter,
    int m0, char* lds, int tid, f32x4 acc[2][4]) {
  const int wave = tid >> 6, lane = tid & 63;
  const int wr = wave >> 2, wc = wave & 3;

#pragma unroll
  for (int m = 0; m < 2; m++)
#pragma unroll
    for (int n = 0; n < 4; n++)
#pragma unroll
      for (int e = 0; e < 4; e++) acc[m][n][e] = 0.f;

  const char* aP0 = A0 + (size_t)(m0 + (tid >> 3)) * 512 + (tid & 7) * 16;
  const char* aP1 = A1 + (size_t)(m0 + (tid >> 3)) * 512 + (tid & 7) * 16;

  auto STAGE = [&](int bsel, int kb) {
    char* bufA = lds + bsel * 41216;
    char* bufW = bufA + 8192;
    const char* asrc = (KBiter == 8)
        ? (kb < 4 ? aP0 + kb * 128 : aP1 + (kb - 4) * 128)
        : aP0 + kb * 128;
    gload_lds16(asrc, bufA + wave * 1024);
    const char* wsrc = wTile + (size_t)kb * 32768 + wave * 1024 + lane * 16;
#pragma unroll
    for (int it = 0; it < 4; ++it)
      gload_lds16(wsrc + it * 8192, bufW + it * 8192 + wave * 1024);
  };

  __syncthreads();            // prior phase done with both buffers (+store drain)
  STAGE(0, 0);
  for (int kb = 0; kb < KBiter; ++kb) {
    __syncthreads();          // STAGE(kb) landed; buf[(kb+1)&1] free for prefetch
    if (kb + 1 < KBiter) STAGE((kb + 1) & 1, kb + 1);
    char* bufA = lds + (kb & 1) * 41216;
    char* bufW = bufA + 8192;
#pragma unroll
    for (int kk = 0; kk < 2; ++kk) {
      const int kbyte = kk * 64 + (lane >> 4) * 16;
      h16x8 af[2], bfr[4];
#pragma unroll
      for (int mt = 0; mt < 2; ++mt) {
        int r = wr * 32 + mt * 16 + (lane & 15);
        af[mt] = *(const h16x8*)(bufA + r * 128 + (kbyte ^ ((r & 7) << 4)));
      }
#pragma unroll
      for (int nt = 0; nt < 4; ++nt) {
        int c = wc * 64 + nt * 16 + (lane & 15);
        bfr[nt] = *(const h16x8*)(bufW + c * 128 + (kbyte ^ ((c & 7) << 4)));
      }
#pragma unroll
      for (int mt = 0; mt < 2; ++mt)
#pragma unroll
        for (int nt = 0; nt < 4; ++nt)
          acc[mt][nt] = __builtin_amdgcn_mfma_f32_16x16x32_f16(af[mt], bfr[nt], acc[mt][nt], 0, 0, 0);
    }
  }
}

// ---- LSTM epilogue for one nb tile: lane owns j = nb*64 + wc*16 + (lane&15) ----
__device__ __forceinline__ void lstm_ep(
    f32x4 acc[2][4], int m0, int nb, int tid, const float* bias,
    const float* wih0x, const float* xbase, int xstride, int hasx, int skipc,
    h16* Cst, char* hout) {
  const int wave = tid >> 6, lane = tid & 63;
  const int wr = wave >> 2, wc = wave & 3;
  const int j = nb * 64 + wc * 16 + (lane & 15);
  const float bi = bias[j], bff = bias[256 + j], bg = bias[512 + j], bo = bias[768 + j];
  float wi0 = 0, wi1 = 0, wf0 = 0, wf1 = 0, wg0 = 0, wg1 = 0, wo0 = 0, wo1 = 0;
  if (hasx) {
    wi0 = wih0x[2 * j];           wi1 = wih0x[2 * j + 1];
    wf0 = wih0x[2 * (256 + j)];   wf1 = wih0x[2 * (256 + j) + 1];
    wg0 = wih0x[2 * (512 + j)];   wg1 = wih0x[2 * (512 + j) + 1];
    wo0 = wih0x[2 * (768 + j)];   wo1 = wih0x[2 * (768 + j) + 1];
  }
#pragma unroll
  for (int mt = 0; mt < 2; ++mt) {
#pragma unroll
    for (int e = 0; e < 4; e++) {
      const int b = m0 + wr * 32 + mt * 16 + (lane >> 4) * 4 + e;
      float vi = acc[mt][0][e] + bi;
      float vf = acc[mt][1][e] + bff;
      float vg = acc[mt][2][e] + bg;
      float vo = acc[mt][3][e] + bo;
      if (hasx) {
        const float x0 = xbase[(size_t)b * xstride];
        const float x1 = xbase[(size_t)b * xstride + 1];
        vi += x0 * wi0 + x1 * wi1;
        vf += x0 * wf0 + x1 * wf1;
        vg += x0 * wg0 + x1 * wg1;
        vo += x0 * wo0 + x1 * wo1;
      }
      const size_t ci = (size_t)b * 256 + j;
      float cn = sigf(vi) * tanh_f(vg);
      if (!skipc) cn += sigf(vf) * (float)Cst[ci];
      float h = sigf(vo) * tanh_f(cn);
      Cst[ci] = (h16)cn;
      *(h16*)(hout + (size_t)b * 512 + (((unsigned)j * 2) ^ (unsigned)((b & 7) << 4))) = (h16)h;
    }
  }
}

// ---- one full LSTM cell for this block's 64 rows (all 1024 gate cols) ----
__device__ void cell_block(const char* A0, const char* A1, const char* Wp,
                           int KBiter, int KBpack,
                           const float* bias, const float* wih0x, const float* xbase,
                           int xstride, int hasx, int skipc,
                           h16* Cst, char* hout, int m0, char* lds, int tid) {
  for (int nb = 0; nb < 4; ++nb) {
    f32x4 acc[2][4];
    gemm_tile(A0, A1, Wp + (size_t)nb * KBpack * 32768, KBiter, m0, lds, tid, acc);
    lstm_ep(acc, m0, nb, tid, bias, wih0x, xbase, xstride, hasx, skipc, Cst, hout);
  }
}

// ---- L1.l0 @ t=0 pointwise (c=0): gates = bias + x*Wih0 ----
__device__ void l0t0_block(const float* x, const float* wih0, const float* bias,
                           h16* C, char* hout, int m0, int tid) {
  const int r = tid & 63, jg = tid >> 6;
  const size_t b = (size_t)(m0 + r);
  const float x0 = x[b * 16], x1 = x[b * 16 + 1];
#pragma unroll
  for (int q = 0; q < 4; ++q) {
    const int j0 = jg * 32 + q * 8;
    h16 cc[8], hh[8];
#pragma unroll
    for (int u = 0; u < 8; ++u) {
      int j = j0 + u;
      float vi = bias[j]       + x0 * wih0[2 * j]         + x1 * wih0[2 * j + 1];
      float vg = bias[512 + j] + x0 * wih0[2 * (512 + j)] + x1 * wih0[2 * (512 + j) + 1];
      float vo = bias[768 + j] + x0 * wih0[2 * (768 + j)] + x1 * wih0[2 * (768 + j) + 1];
      float cn = sigf(vi) * tanh_f(vg);
      hh[u] = (h16)(sigf(vo) * tanh_f(cn));
      cc[u] = (h16)cn;
    }
    *(h16x8*)(C + b * 256 + j0) = *(h16x8*)cc;
    *(h16x8*)(hout + b * 512 + (((unsigned)j0 * 2) ^ (unsigned)((b & 7) << 4))) = *(h16x8*)hh;
  }
}

// ---- fused fc1+relu+fc2+pos+out for this block's rows ----
__device__ void head_block(const char* A, const char* wpf1, const float* b1,
                           const float* w2, const float* b2, float* pos, float* out,
                           int s, int m0, char* lds, int tid) {
  f32x4 acc[2][4];
  gemm_tile(A, A, wpf1, 4, m0, lds, tid, acc);
  __syncthreads();
  h16* strip = (h16*)lds;          // [64][262] fp16 = 33.5KB, reuses buf0
  const int wave = tid >> 6, lane = tid & 63;
  const int wr = wave >> 2, wc = wave & 3;
#pragma unroll
  for (int nt = 0; nt < 4; ++nt) {
    const int n = wc * 64 + nt * 16 + (lane & 15);
    const float bn = b1[n];
#pragma unroll
    for (int mt = 0; mt < 2; ++mt)
#pragma unroll
      for (int e = 0; e < 4; ++e) {
        const int bl = wr * 32 + mt * 16 + (lane >> 4) * 4 + e;
        float v = acc[mt][nt][e] + bn;
        strip[bl * 262 + n] = (h16)(v > 0.f ? v : 0.f);
      }
  }
  __syncthreads();
  if (tid < 128) {
    const int bl2 = tid >> 1, comp = tid & 1;
    const float* wrow = w2 + comp * 256;
    float a = 0.f;
#pragma unroll 8
    for (int n = 0; n < 256; ++n) a += (float)strip[bl2 * 262 + n] * wrow[n];
    const size_t b = (size_t)(m0 + bl2);
    float p = pos[2 * b + comp] + a + b2[comp];
    pos[2 * b + comp] = p;
    out[b * (NPRED * 2) + s * 2 + comp] = p;
  }
  __syncthreads();
}

// ---- persistent whole-network kernel ----
struct AllArgs {
  const float* x;
  const float* wih0;
  const char* wp10; const char* wp0; const char* wp1; const char* wp2; const char* wpf1;
  const float* biasc;
  const float* fc1_b; const float* fc2_w; const float* fc2_b;
  char* h0[2]; char* h1[2]; char* h2[2]; char* h3[2];
  h16* C0; h16* C1; h16* C2; h16* C3;
  float* pos;
  float* out;
};

__global__ __launch_bounds__(512, 2) void lstm_all(AllArgs a) {
  __shared__ __align__(16) char lds[84992];   // 2x41216 dbuf; >81920 forces 1 block/CU
  const int tid = threadIdx.x;
  const int m0 = blockIdx.x * RPB;

  // pos init (own rows)
  if (tid < 128) {
    const size_t b = (size_t)(m0 + (tid >> 1));
    a.pos[2 * b + (tid & 1)] = a.x[b * 16 + 14 + (tid & 1)];
  }

  // ---- encoder t=0 (skipc; fixed KBpack slab stride for upper cells) ----
  l0t0_block(a.x, a.wih0, a.biasc, a.C0, a.h0[0], m0, tid);
  cell_block(a.h0[0], a.h0[0], a.wp0, 4, 8, a.biasc + 1024, nullptr, nullptr, 0, 0, 1, a.C1, a.h1[0], m0, lds, tid);
  cell_block(a.h1[0], a.h1[0], a.wp1, 4, 8, a.biasc + 2048, nullptr, nullptr, 0, 0, 1, a.C2, a.h2[0], m0, lds, tid);
  cell_block(a.h2[0], a.h2[0], a.wp2, 4, 8, a.biasc + 3072, nullptr, nullptr, 0, 0, 1, a.C3, a.h3[0], m0, lds, tid);

  // ---- encoder t=1..7 ----
  for (int t = 1; t < Tseq; ++t) {
    const int cur = t & 1, prev = cur ^ 1;
    cell_block(a.h0[prev], a.h0[prev], a.wp10, 4, 4, a.biasc, a.wih0, a.x + t * 2, 16, 1, 0, a.C0, a.h0[cur], m0, lds, tid);
    cell_block(a.h0[cur], a.h1[prev], a.wp0, 8, 8, a.biasc + 1024, nullptr, nullptr, 0, 0, 0, a.C1, a.h1[cur], m0, lds, tid);
    cell_block(a.h1[cur], a.h2[prev], a.wp1, 8, 8, a.biasc + 2048, nullptr, nullptr, 0, 0, 0, a.C2, a.h2[cur], m0, lds, tid);
    cell_block(a.h2[cur], a.h3[prev], a.wp2, 8, 8, a.biasc + 3072, nullptr, nullptr, 0, 0, 0, a.C3, a.h3[cur], m0, lds, tid);
  }

  // ---- decoder s=0..11 ----
  for (int s = 0; s < NPRED; ++s) {
    const int u = Tseq + s, cur = u & 1, prev = cur ^ 1;
    cell_block(a.h0[prev], a.h0[prev], a.wp10, 4, 4, a.biasc, a.wih0, a.pos, 2, 1, 0, a.C0, a.h0[cur], m0, lds, tid);
    cell_block(a.h0[cur], a.h1[prev], a.wp0, 8, 8, a.biasc + 1024, nullptr, nullptr, 0, 0, 0, a.C1, a.h1[cur], m0, lds, tid);
    cell_block(a.h1[cur], a.h2[prev], a.wp1, 8, 8, a.biasc + 2048, nullptr, nullptr, 0, 0, 0, a.C2, a.h2[cur], m0, lds, tid);
    cell_block(a.h2[cur], a.h3[prev], a.wp2, 8, 8, a.biasc + 3072, nullptr, nullptr, 0, 0, 0, a.C3, a.h3[cur], m0, lds, tid);
    head_block(a.h3[cur], a.wpf1, a.fc1_b, a.fc2_w, a.fc2_b, a.pos, a.out, s, m0, lds, tid);
  }
}

// ---------- host ----------
extern "C" void kernel_launch(void* const* d_in, const int* in_sizes, int n_in,
                              void* d_out, int out_size, void* d_ws, size_t ws_size,
                              hipStream_t stream) {
  const float* x      = (const float*)d_in[0];
  const float* Wih[4] = {(const float*)d_in[1], (const float*)d_in[5],
                         (const float*)d_in[9], (const float*)d_in[13]};
  const float* Whh[4] = {(const float*)d_in[2], (const float*)d_in[6],
                         (const float*)d_in[10], (const float*)d_in[14]};
  const float* bih[4] = {(const float*)d_in[3], (const float*)d_in[7],
                         (const float*)d_in[11], (const float*)d_in[15]};
  const float* bhh[4] = {(const float*)d_in[4], (const float*)d_in[8],
                         (const float*)d_in[12], (const float*)d_in[16]};
  const float* fc1_w = (const float*)d_in[17];
  const float* fc1_b = (const float*)d_in[18];
  const float* fc2_w = (const float*)d_in[19];
  const float* fc2_b = (const float*)d_in[20];

  char* ws = (char*)d_ws;
  size_t off = 0;
  auto alloc = [&](size_t bytes) -> char* {
    char* p = ws + off;
    off += (bytes + 255) & ~(size_t)255;
    return p;
  };

  h16* Cs[4];
  for (int l = 0; l < 4; l++) Cs[l] = (h16*)alloc((size_t)Bsz * 256 * 2);
  char* hb[4][2];
  for (int l = 0; l < 4; l++) {
    hb[l][0] = alloc((size_t)Bsz * 512);
    hb[l][1] = alloc((size_t)Bsz * 512);
  }
  float* pos = (float*)alloc((size_t)Bsz * 2 * 4);
  float* biasc = (float*)alloc(4 * 1024 * 4);
  h16* wp10 = (h16*)alloc((size_t)1024 * 256 * 2);
  h16* wp[3];
  for (int i = 0; i < 3; i++) wp[i] = (h16*)alloc((size_t)1024 * 512 * 2);
  h16* wpf1 = (h16*)alloc((size_t)256 * 256 * 2);

  if (ws_size < off) {
    mark_r14<<<dim3(1), dim3(64), 0, stream>>>((float*)d_out);
    return;
  }

  pack_w<<<dim3((1024 * 256 + 255) / 256), dim3(256), 0, stream>>>(wp10, Whh[0], Whh[0], 256, 256, 1024, 1);
  pack_w<<<dim3((1024 * 512 + 255) / 256), dim3(256), 0, stream>>>(wp[0], Wih[1], Whh[1], 256, 512, 1024, 1);
  pack_w<<<dim3((1024 * 512 + 255) / 256), dim3(256), 0, stream>>>(wp[1], Wih[2], Whh[2], 256, 512, 1024, 1);
  pack_w<<<dim3((1024 * 512 + 255) / 256), dim3(256), 0, stream>>>(wp[2], Wih[3], Whh[3], 256, 512, 1024, 1);
  pack_w<<<dim3((256 * 256 + 255) / 256), dim3(256), 0, stream>>>(wpf1, fc1_w, fc1_w, 256, 256, 256, 0);
  for (int l = 0; l < 4; l++)
    add_bias<<<dim3(4), dim3(256), 0, stream>>>(biasc + l * 1024, bih[l], bhh[l]);

  AllArgs a;
  a.x = x; a.wih0 = Wih[0];
  a.wp10 = (const char*)wp10; a.wp0 = (const char*)wp[0];
  a.wp1 = (const char*)wp[1]; a.wp2 = (const char*)wp[2];
  a.wpf1 = (const char*)wpf1;
  a.biasc = biasc;
  a.fc1_b = fc1_b; a.fc2_w = fc2_w; a.fc2_b = fc2_b;
  for (int l = 0; l < 2; l++) {
    a.h0[l] = hb[0][l]; a.h1[l] = hb[1][l]; a.h2[l] = hb[2][l]; a.h3[l] = hb[3][l];
  }
  a.C0 = Cs[0]; a.C1 = Cs[1]; a.C2 = Cs[2]; a.C3 = Cs[3];
  a.pos = pos; a.out = (float*)d_out;

  lstm_all<<<dim3(Bsz / RPB), dim3(512), 0, stream>>>(a);
}